// Round 13
// baseline (345.024 us; speedup 1.0000x reference)
//
#include <hip/hip_runtime.h>
#include <math.h>
#include <float.h>

// Problem constants
#define BATCH 16
#define CHN   256
#define HH    32
#define WW    32
#define NTOK  (BATCH*HH*WW)   // 16384 tokens
#define DIMS  256             // embedding dim
#define KCODES 8192           // codebook entries

// Stage-1 tiling
#define MBLK 128                          // tokens per block (4 waves x 32)
#define NSPLIT 8                          // grid = 128*8 = 1024 blocks
#define CODES_PER_SPLIT (KCODES/NSPLIT)   // 1024
#define CCHUNK 64                         // codes per chunk
#define NCHUNKS (CODES_PER_SPLIT/CCHUNK)  // 16
#define BROW 256                          // packed Bh row length in f16
#define BTSTR 264                         // LDS B row stride in f16 (256+8 pad; 528B mod 128 = 16 -> 2-way-free)

// Margin: score-difference error sigma ~2.7e-3; 0.02 = ~7.4 sigma.
#define MARGIN 0.02f
#define UCAP 4096
#define RT 8                              // refine: tokens per tile
#define RSLICES 32                        // refine: token slices (grid = 32*256)

#define GATHER_BLOCKS 4096

// ws layout (bytes) — all offsets 8-aligned where needed
#define WS_CB2   0
#define WS_IDX   32768
#define WS_PART  (WS_IDX + NTOK*4)
#define WS_UCNT  (WS_PART + GATHER_BLOCKS*4)   // 4 B counter (in 64 B slot)
#define WS_ULIST (WS_UCNT + 64)
#define WS_UKEY  (WS_ULIST + UCAP*4 + 64)      // 131200: 8-byte aligned (u64 array!)
// d_out scratch offsets (bytes): bh at 0 (4MB); stage-1 outs; ucx (4MB)
#define DO_BV1 (4u*1024*1024)
#define DO_BI1 (DO_BV1 + NSPLIT*NTOK*4)
#define DO_BV2 (DO_BI1 + NSPLIT*NTOK*4)
#define DO_UCX (6u*1024*1024)

typedef _Float16 f16;
typedef f16 f16x8 __attribute__((ext_vector_type(8)));
typedef float f32x4 __attribute__((ext_vector_type(4)));

// ---------------------------------------------------------------------------
// Kernel 1: cb2[k] = sum_d codebook[k][d]^2 (fp32). One wave per row.
// Also zeroes the uncertain-token counter (runs before combine_kernel).
__global__ void cb2_kernel(const float* __restrict__ codebook, float* __restrict__ cb2,
                           int* __restrict__ ucnt) {
    if (blockIdx.x == 0 && threadIdx.x == 0) *ucnt = 0;
    int wv   = threadIdx.x >> 6;
    int lane = threadIdx.x & 63;
    int row  = blockIdx.x * 4 + wv;
    const float4 v = *(const float4*)&codebook[(size_t)row * DIMS + lane * 4];
    float s = v.x*v.x + v.y*v.y + v.z*v.z + v.w*v.w;
    #pragma unroll
    for (int m = 32; m >= 1; m >>= 1) s += __shfl_xor(s, m, 64);
    if (lane == 0) cb2[row] = s;
}

// ---------------------------------------------------------------------------
// Kernel 2: pack codebook high limb only: bh[code][k] = f16(c).
__global__ void bpackh_kernel(const float* __restrict__ codebook, f16* __restrict__ bh) {
    int code = blockIdx.x;
    int k = threadIdx.x;
    bh[(size_t)code * BROW + k] = (f16)codebook[(size_t)code * DIMS + k];
}

// ---------------------------------------------------------------------------
// Kernel 3: 1-limb MFMA approx-distance GEMM + running TOP-2 argmin.
// score = cb2[k] - 2*dot(f16(x), f16(c)), fp32 MFMA accumulate.
// CHANGE vs round 12: full 256-dim chunk staged per barrier pair (was 2x128)
// -> barrier pairs 32->16/block, compute phase between barriers doubles
// (32 ds_read + 64 MFMA ~ 700 cyc) which now covers the ~400cyc L2 latency
// of the T14 prefetch. Fragment k-mapping unchanged.
__global__ __launch_bounds__(256, 2) void argmin1_kernel(
    const float* __restrict__ latent, const f16* __restrict__ bh,
    const float* __restrict__ cb2,
    float* __restrict__ bv1_ws, int* __restrict__ bi1_ws, float* __restrict__ bv2_ws)
{
    __shared__ f16 Bt[CCHUNK * BTSTR];    // 64 x 264 f16 = 33792 B

    const int tid = threadIdx.x;
    const int wv = tid >> 6, l = tid & 63;
    const int js = blockIdx.x >> 7;        // code split 0..7
    const int bm = blockIdx.x & 127;       // token block 0..127
    const int n0 = bm * MBLK;
    const int bb = n0 >> 10, hw0 = n0 & 1023;
    const int code_base = js * CODES_PER_SPLIT;

    // ---- A prologue: direct global->register f16 fragments (mf=2).
    // fragment reg j -> k = kst*32 + (l>>4)*8 + j.
    f16x8 Ah[2][8];
    #pragma unroll
    for (int mfi = 0; mfi < 2; ++mfi) {
        const float* latb = latent + (size_t)bb * (CHN*HH*WW) + hw0
                          + wv*32 + mfi*16 + (l & 15);
        #pragma unroll
        for (int kst = 0; kst < 8; ++kst) {
            f16x8 h;
            #pragma unroll
            for (int j = 0; j < 8; ++j)
                h[j] = (f16)latb[(size_t)(kst*32 + ((l >> 4) << 3) + j) * (HH*WW)];
            Ah[mfi][kst] = h;
        }
    }

    f32x4 acc[2][4];
    float bv1[2][4], bv2[2][4];
    int   bi1[2][4];
    #pragma unroll
    for (int mfi = 0; mfi < 2; ++mfi)
    #pragma unroll
    for (int nf = 0; nf < 4; ++nf) acc[mfi][nf] = (f32x4)0.0f;
    #pragma unroll
    for (int mfi = 0; mfi < 2; ++mfi)
    #pragma unroll
    for (int r = 0; r < 4; ++r) {
        bv1[mfi][r] = FLT_MAX; bv2[mfi][r] = FLT_MAX; bi1[mfi][r] = 0x7fffffff;
    }

    // staging map: thread (srow = tid>>3, s8 = tid&7) covers rows srow,
    // srow+32; 16B slots s8+8g, g=0..3 (8 float4/thread = full 256-dim rows).
    const int srow = tid >> 3;
    const int s8   = tid & 7;

    float4 stgA[4], stgB[4];
    {   // prologue: chunk 0
        const float4* pA = (const float4*)(bh + (size_t)(code_base + srow) * BROW);
        const float4* pB = (const float4*)(bh + (size_t)(code_base + srow + 32) * BROW);
        #pragma unroll
        for (int g = 0; g < 4; ++g) {
            stgA[g] = pA[s8 + 8*g];
            stgB[g] = pB[s8 + 8*g];
        }
    }

    for (int chunk = 0; chunk < NCHUNKS; ++chunk) {
        __syncthreads();           // prior chunk's reads done -> Bt free
        #pragma unroll
        for (int g = 0; g < 4; ++g) {
            *(float4*)&Bt[srow*BTSTR + (s8 + 8*g)*8]        = stgA[g];
            *(float4*)&Bt[(srow+32)*BTSTR + (s8 + 8*g)*8]   = stgB[g];
        }
        __syncthreads();

        if (chunk + 1 < NCHUNKS) {   // T14 prefetch next chunk (covered by 64 MFMA below)
            const float4* pA = (const float4*)(bh + (size_t)(code_base + (chunk+1)*CCHUNK + srow) * BROW);
            const float4* pB = (const float4*)(bh + (size_t)(code_base + (chunk+1)*CCHUNK + srow + 32) * BROW);
            #pragma unroll
            for (int g = 0; g < 4; ++g) {
                stgA[g] = pA[s8 + 8*g];
                stgB[g] = pB[s8 + 8*g];
            }
        }

        #pragma unroll
        for (int kst = 0; kst < 8; ++kst) {
            #pragma unroll
            for (int nf = 0; nf < 4; ++nf) {
                const f16x8 bf = *(const f16x8*)&Bt[(nf*16 + (l & 15))*BTSTR
                                                    + (kst*4 + (l >> 4))*8];
                acc[0][nf] = __builtin_amdgcn_mfma_f32_16x16x32_f16(Ah[0][kst], bf, acc[0][nf], 0, 0, 0);
                acc[1][nf] = __builtin_amdgcn_mfma_f32_16x16x32_f16(Ah[1][kst], bf, acc[1][nf], 0, 0, 0);
            }
        }

        // fold: top-2 per token-slot (codes ascend -> np first-occurrence)
        const int code0 = code_base + chunk*CCHUNK;
        #pragma unroll
        for (int nf = 0; nf < 4; ++nf) {
            const int code = code0 + nf*16 + (l & 15);
            const float c2 = cb2[code];
            #pragma unroll
            for (int mfi = 0; mfi < 2; ++mfi)
            #pragma unroll
            for (int r = 0; r < 4; ++r) {
                float v = fmaf(acc[mfi][nf][r], -2.0f, c2);
                if (v < bv1[mfi][r]) {
                    bv2[mfi][r] = bv1[mfi][r];
                    bv1[mfi][r] = v; bi1[mfi][r] = code;
                } else if (v < bv2[mfi][r]) {
                    bv2[mfi][r] = v;
                }
                acc[mfi][nf][r] = 0.0f;
            }
        }
    }

    // ---- reduce top-2 across the 16 code-lanes; write per-token ----
    #pragma unroll
    for (int mfi = 0; mfi < 2; ++mfi)
    #pragma unroll
    for (int r = 0; r < 4; ++r) {
        float v1 = bv1[mfi][r], v2 = bv2[mfi][r];
        int i1 = bi1[mfi][r];
        #pragma unroll
        for (int m = 1; m <= 8; m <<= 1) {
            float ov1 = __shfl_xor(v1, m, 64);
            int   oi1 = __shfl_xor(i1, m, 64);
            float ov2 = __shfl_xor(v2, m, 64);
            if (ov1 < v1 || (ov1 == v1 && oi1 < i1)) {
                v2 = fminf(v1, ov2); v1 = ov1; i1 = oi1;
            } else {
                v2 = fminf(v2, ov1);
            }
        }
        if ((l & 15) == 0) {
            int tt = n0 + wv*32 + mfi*16 + ((l >> 4) << 2) + r;
            bv1_ws[js*NTOK + tt] = v1;
            bi1_ws[js*NTOK + tt] = i1;
            bv2_ws[js*NTOK + tt] = v2;
        }
    }
}

// ---------------------------------------------------------------------------
// Kernel 4: merge splits, write idx, flag uncertain tokens (gap < MARGIN).
__global__ void combine_kernel(const float* __restrict__ bv1_ws,
                               const int* __restrict__ bi1_ws,
                               const float* __restrict__ bv2_ws,
                               int* __restrict__ idx_ws,
                               int* __restrict__ ucnt,
                               int* __restrict__ ulist,
                               unsigned long long* __restrict__ ukey)
{
    int n = blockIdx.x * 256 + threadIdx.x;
    float v1 = bv1_ws[n]; int i1 = bi1_ws[n]; float v2 = bv2_ws[n];
    #pragma unroll
    for (int js = 1; js < NSPLIT; ++js) {
        float ov1 = bv1_ws[js*NTOK + n];
        int   oi1 = bi1_ws[js*NTOK + n];
        float ov2 = bv2_ws[js*NTOK + n];
        if (ov1 < v1 || (ov1 == v1 && oi1 < i1)) {
            v2 = fminf(v1, ov2); v1 = ov1; i1 = oi1;
        } else {
            v2 = fminf(v2, ov1);
        }
    }
    idx_ws[n] = i1;
    if (v2 - v1 < MARGIN) {
        int slot = atomicAdd(ucnt, 1);
        if (slot < UCAP) {
            ulist[slot] = n;
            ukey[n] = ~0ull;
        }
    }
}

// ---------------------------------------------------------------------------
// Kernel 5: gather uncertain tokens' x vectors into dense rows.
__global__ void gathercands_kernel(const float* __restrict__ latent,
                                   const int* __restrict__ ulist,
                                   const int* __restrict__ ucnt,
                                   float* __restrict__ ucx)
{
    int cnt = *ucnt; if (cnt > UCAP) cnt = UCAP;
    int t = threadIdx.x;
    for (int i = blockIdx.x; i < cnt; i += gridDim.x) {
        int n = ulist[i];
        int b = n >> 10, hw = n & 1023;
        ucx[(size_t)i*256 + t] = latent[(size_t)b*(CHN*HH*WW) + (size_t)t*(HH*WW) + hw];
    }
}

// ---------------------------------------------------------------------------
// Kernel 6: exact fp32 refine — uncertain tokens vs ALL codes.
// (byte-identical to the passing round-12 kernel)
__global__ __launch_bounds__(256) void refine_kernel(
    const float* __restrict__ ucx, const int* __restrict__ ulist,
    const int* __restrict__ ucnt, const float* __restrict__ codebook,
    const float* __restrict__ cb2, unsigned long long* __restrict__ ukey)
{
    __shared__ float sx[RT*256];                  // 8 KB
    __shared__ unsigned long long wkey[RT][4];

    int cnt = *ucnt; if (cnt > UCAP) cnt = UCAP;
    if (cnt == 0) return;
    const int slice = blockIdx.x >> 8;            // 0..31
    const int cg    = blockIdx.x & 255;           // code group
    const int t = threadIdx.x;
    const int w = t >> 6, l = t & 63;
    const int q = t & 7;                          // dim slice
    const int code = cg * 32 + (t >> 3);

    const int chunk = (cnt + RSLICES - 1) / RSLICES;
    const int s_beg = slice * chunk;
    const int s_end = (s_beg + chunk < cnt) ? s_beg + chunk : cnt;
    const int nslice = s_end - s_beg;
    if (nslice <= 0) return;
    const int ntiles = (nslice + RT - 1) / RT;

    float4 cbr[8];
    #pragma unroll
    for (int e = 0; e < 8; ++e)
        cbr[e] = *(const float4*)&codebook[(size_t)code*DIMS + e*32 + q*4];
    const float c2 = cb2[code];

    float4 pr0, pr1;
    {
        const float4* src = (const float4*)(ucx + (size_t)s_beg*256);
        pr0 = src[t];
        pr1 = src[t + 256];
    }

    for (int tile = 0; tile < ntiles; ++tile) {
        __syncthreads();                          // sx + wkey consumers done
        *(float4*)&sx[t*4]       = pr0;           // linear: conflict-free
        *(float4*)&sx[(t+256)*4] = pr1;
        __syncthreads();

        if (tile + 1 < ntiles) {                  // T14 prefetch next tile
            const float4* src = (const float4*)(ucx + (size_t)(s_beg + (tile+1)*RT)*256);
            pr0 = src[t];
            pr1 = src[t + 256];
        }

        const int i0 = s_beg + tile * RT;
        #pragma unroll
        for (int tt = 0; tt < RT; ++tt) {
            float d0 = 0.0f, d1 = 0.0f;           // 2 chains for ILP
            #pragma unroll
            for (int e = 0; e < 8; e += 2) {
                const float4 x0 = *(const float4*)&sx[tt*256 + e*32 + q*4];
                const float4 x1 = *(const float4*)&sx[tt*256 + (e+1)*32 + q*4];
                d0 = fmaf(x0.x, cbr[e].x, d0);
                d0 = fmaf(x0.y, cbr[e].y, d0);
                d0 = fmaf(x0.z, cbr[e].z, d0);
                d0 = fmaf(x0.w, cbr[e].w, d0);
                d1 = fmaf(x1.x, cbr[e+1].x, d1);
                d1 = fmaf(x1.y, cbr[e+1].y, d1);
                d1 = fmaf(x1.z, cbr[e+1].z, d1);
                d1 = fmaf(x1.w, cbr[e+1].w, d1);
            }
            float dot = d0 + d1;
            #pragma unroll
            for (int m = 1; m <= 4; m <<= 1) dot += __shfl_xor(dot, m, 64);
            const float s = fmaf(dot, -2.0f, c2);
            unsigned mm = __float_as_uint(s);     // monotone total-order map
            mm = (mm & 0x80000000u) ? ~mm : (mm | 0x80000000u);
            unsigned long long key = ((unsigned long long)mm << 32) | (unsigned)code;
            #pragma unroll
            for (int m = 8; m <= 32; m <<= 1) {
                unsigned long long ok = __shfl_xor(key, m, 64);
                if (ok < key) key = ok;
            }
            if (l == 0) wkey[tt][w] = key;
        }
        __syncthreads();
        if (t < RT && i0 + t < s_end) {
            unsigned long long k = wkey[t][0];
            if (wkey[t][1] < k) k = wkey[t][1];
            if (wkey[t][2] < k) k = wkey[t][2];
            if (wkey[t][3] < k) k = wkey[t][3];
            atomicMin(&ukey[ulist[i0 + t]], k);
        }
    }
}

// ---------------------------------------------------------------------------
// Kernel 7: write refined indices back.
__global__ void fixup_kernel(const int* __restrict__ ulist,
                             const int* __restrict__ ucnt,
                             const unsigned long long* __restrict__ ukey,
                             int* __restrict__ idx_ws)
{
    int cnt = *ucnt; if (cnt > UCAP) cnt = UCAP;
    int i = blockIdx.x * 256 + threadIdx.x;
    if (i < cnt) {
        int n = ulist[i];
        unsigned long long k = ukey[n];
        if (k != ~0ull) idx_ws[n] = (int)(k & 0xffffffffull);
    }
}

// ---------------------------------------------------------------------------
// Kernel 8: gather codebook rows -> quantized output (NCHW), loss partials.
__global__ __launch_bounds__(256) void gather_kernel(
    const float* __restrict__ latent, const float* __restrict__ codebook,
    const int* __restrict__ idx_ws, float* __restrict__ out,
    float* __restrict__ partials)
{
    int gid = blockIdx.x * 256 + threadIdx.x;
    int o = gid * 4;
    int w0 = o & 31;
    int h  = (o >> 5) & 31;
    int c  = (o >> 10) & 255;
    int b  = o >> 18;
    int nb = (b << 10) + (h << 5) + w0;

    float4 x = *(const float4*)&latent[o];
    float4 q;
    q.x = codebook[(size_t)idx_ws[nb + 0] * DIMS + c];
    q.y = codebook[(size_t)idx_ws[nb + 1] * DIMS + c];
    q.z = codebook[(size_t)idx_ws[nb + 2] * DIMS + c];
    q.w = codebook[(size_t)idx_ws[nb + 3] * DIMS + c];
    *(float4*)&out[o] = q;

    float dx = q.x - x.x, dy = q.y - x.y, dz = q.z - x.z, dw = q.w - x.w;
    float s = dx*dx + dy*dy + dz*dz + dw*dw;
    #pragma unroll
    for (int m = 32; m >= 1; m >>= 1) s += __shfl_xor(s, m, 64);

    __shared__ float wsum[4];
    int lane = threadIdx.x & 63, wv = threadIdx.x >> 6;
    if (lane == 0) wsum[wv] = s;
    __syncthreads();
    if (threadIdx.x == 0)
        partials[blockIdx.x] = wsum[0] + wsum[1] + wsum[2] + wsum[3];
}

// ---------------------------------------------------------------------------
// Kernel 9: final loss reduction.
__global__ void loss_kernel(const float* __restrict__ partials, float* __restrict__ out) {
    __shared__ double sd[256];
    double s = 0.0;
    #pragma unroll
    for (int r = 0; r < GATHER_BLOCKS / 256; ++r)
        s += (double)partials[threadIdx.x + r * 256];
    sd[threadIdx.x] = s;
    __syncthreads();
    for (int k = 128; k >= 1; k >>= 1) {
        if (threadIdx.x < k) sd[threadIdx.x] += sd[threadIdx.x + k];
        __syncthreads();
    }
    if (threadIdx.x == 0) {
        float loss = (float)(sd[0] / (double)((size_t)NTOK * DIMS));
        out[(size_t)NTOK * DIMS + 0] = loss;
        out[(size_t)NTOK * DIMS + 1] = loss;
    }
}

// ---------------------------------------------------------------------------
extern "C" void kernel_launch(void* const* d_in, const int* in_sizes, int n_in,
                              void* d_out, int out_size, void* d_ws, size_t ws_size,
                              hipStream_t stream) {
    (void)in_sizes; (void)n_in; (void)out_size; (void)ws_size;
    const float* latent   = (const float*)d_in[0];
    const float* codebook = (const float*)d_in[1];
    float* out = (float*)d_out;
    char*  ws  = (char*)d_ws;
    char*  ob  = (char*)d_out;

    float* cb2  = (float*)(ws + WS_CB2);
    int*   idx  = (int*)(ws + WS_IDX);
    float* part = (float*)(ws + WS_PART);
    int*   ucnt = (int*)(ws + WS_UCNT);
    int*   ulist = (int*)(ws + WS_ULIST);
    unsigned long long* ukey = (unsigned long long*)(ws + WS_UKEY);  // 8-aligned

    // d_out doubles as scratch (all consumed before gather overwrites it):
    //   bh [0,4MB) f16 plane; bv1/bi1/bv2 [4,5.5MB); ucx [6,10MB)
    f16*   bh  = (f16*)ob;
    float* bv1 = (float*)(ob + DO_BV1);
    int*   bi1 = (int*)(ob + DO_BI1);
    float* bv2 = (float*)(ob + DO_BV2);
    float* ucx = (float*)(ob + DO_UCX);

    cb2_kernel<<<KCODES / 4, 256, 0, stream>>>(codebook, cb2, ucnt);
    bpackh_kernel<<<KCODES, 256, 0, stream>>>(codebook, bh);
    argmin1_kernel<<<(NTOK / MBLK) * NSPLIT, 256, 0, stream>>>(latent, bh, cb2, bv1, bi1, bv2);
    combine_kernel<<<NTOK / 256, 256, 0, stream>>>(bv1, bi1, bv2, idx, ucnt, ulist, ukey);
    gathercands_kernel<<<256, 256, 0, stream>>>(latent, ulist, ucnt, ucx);
    refine_kernel<<<RSLICES * 256, 256, 0, stream>>>(ucx, ulist, ucnt, codebook, cb2, ukey);
    fixup_kernel<<<UCAP / 256, 256, 0, stream>>>(ulist, ucnt, ukey, idx);
    gather_kernel<<<GATHER_BLOCKS, 256, 0, stream>>>(latent, codebook, idx, out, part);
    loss_kernel<<<1, 256, 0, stream>>>(part, out);
}

// Round 14
// 246.781 us; speedup vs baseline: 1.3981x; 1.3981x over previous
//
#include <hip/hip_runtime.h>
#include <math.h>
#include <float.h>

// Problem constants
#define BATCH 16
#define CHN   256
#define HH    32
#define WW    32
#define NTOK  (BATCH*HH*WW)   // 16384 tokens
#define DIMS  256             // embedding dim
#define KCODES 8192           // codebook entries

// Stage-1 tiling
#define MBLK 128                          // tokens per block (4 waves x 32)
#define NSPLIT 8                          // grid = 128*8 = 1024 blocks
#define CODES_PER_SPLIT (KCODES/NSPLIT)   // 1024
#define CCHUNK 64                         // codes per chunk
#define NCHUNKS (CODES_PER_SPLIT/CCHUNK)  // 16
#define NSTEPS  (2*NCHUNKS)               // 32 stage-steps (128 dims each)
#define BROW 256                          // packed Bh row length in f16
#define BTSTR 136                         // LDS B row stride in f16 (128+8 pad)

// Margin: score-difference error sigma ~2.7e-3; 0.02 = ~7.4 sigma.
#define MARGIN 0.02f
#define UCAP 4096
#define RT 8                              // refine: tokens per tile
#define RSLICES 32                        // refine: token slices (grid = 32*256)

#define GATHER_BLOCKS 4096

// ws layout (bytes) — all offsets 8-aligned where needed
#define WS_CB2   0
#define WS_IDX   32768
#define WS_PART  (WS_IDX + NTOK*4)
#define WS_UCNT  (WS_PART + GATHER_BLOCKS*4)   // 4 B counter (in 64 B slot)
#define WS_ULIST (WS_UCNT + 64)
#define WS_UKEY  (WS_ULIST + UCAP*4 + 64)      // 131200: 8-byte aligned (u64 array!)
// d_out scratch offsets (bytes): bh at 0 (4MB); stage-1 outs; ucx (4MB)
#define DO_BV1 (4u*1024*1024)
#define DO_BI1 (DO_BV1 + NSPLIT*NTOK*4)
#define DO_BV2 (DO_BI1 + NSPLIT*NTOK*4)
#define DO_UCX (6u*1024*1024)

typedef _Float16 f16;
typedef f16 f16x8 __attribute__((ext_vector_type(8)));
typedef float f32x4 __attribute__((ext_vector_type(4)));

// ---------------------------------------------------------------------------
// Kernel 1 (FUSED): cb2[k] = sum_d codebook[k][d]^2 AND bh[k] = f16(codebook[k]).
// One wave per row; also zeroes the uncertain-token counter.
__global__ void cb2pack_kernel(const float* __restrict__ codebook, float* __restrict__ cb2,
                               f16* __restrict__ bh, int* __restrict__ ucnt) {
    if (blockIdx.x == 0 && threadIdx.x == 0) *ucnt = 0;
    int wv   = threadIdx.x >> 6;
    int lane = threadIdx.x & 63;
    int row  = blockIdx.x * 4 + wv;
    const float4 v = *(const float4*)&codebook[(size_t)row * DIMS + lane * 4];
    f16* dst = bh + (size_t)row * BROW + lane * 4;
    dst[0] = (f16)v.x; dst[1] = (f16)v.y; dst[2] = (f16)v.z; dst[3] = (f16)v.w;
    float s = v.x*v.x + v.y*v.y + v.z*v.z + v.w*v.w;
    #pragma unroll
    for (int m = 32; m >= 1; m >>= 1) s += __shfl_xor(s, m, 64);
    if (lane == 0) cb2[row] = s;
}

// ---------------------------------------------------------------------------
// Kernel 2: 1-limb MFMA approx-distance GEMM + running TOP-2 argmin.
// score = cb2[k] - 2*dot(f16(x), f16(c)), fp32 MFMA accumulate.
// CHANGE vs round 12: LDS DOUBLE buffer, ONE barrier per 128-dim step
// (write buf[p^1] overlaps compute on buf[p]); barriers 64 -> 32/block.
// Step size / maps / fold / reduce byte-identical to round 12. Parity via
// 2-step unrolled body with named buffers (rule #20).
__global__ __launch_bounds__(256, 2) void argmin1_kernel(
    const float* __restrict__ latent, const f16* __restrict__ bh,
    const float* __restrict__ cb2,
    float* __restrict__ bv1_ws, int* __restrict__ bi1_ws, float* __restrict__ bv2_ws)
{
    __shared__ f16 BtA[CCHUNK * BTSTR];   // 17408 B
    __shared__ f16 BtB[CCHUNK * BTSTR];   // 17408 B

    const int tid = threadIdx.x;
    const int wv = tid >> 6, l = tid & 63;
    const int js = blockIdx.x >> 7;        // code split 0..7
    const int bm = blockIdx.x & 127;       // token block 0..127
    const int n0 = bm * MBLK;
    const int bb = n0 >> 10, hw0 = n0 & 1023;
    const int code_base = js * CODES_PER_SPLIT;

    // ---- A prologue: direct global->register f16 fragments (mf=2).
    // fragment reg j -> k = kst*32 + (l>>4)*8 + j.
    f16x8 Ah[2][8];
    #pragma unroll
    for (int mfi = 0; mfi < 2; ++mfi) {
        const float* latb = latent + (size_t)bb * (CHN*HH*WW) + hw0
                          + wv*32 + mfi*16 + (l & 15);
        #pragma unroll
        for (int kst = 0; kst < 8; ++kst) {
            f16x8 h;
            #pragma unroll
            for (int j = 0; j < 8; ++j)
                h[j] = (f16)latb[(size_t)(kst*32 + ((l >> 4) << 3) + j) * (HH*WW)];
            Ah[mfi][kst] = h;
        }
    }

    f32x4 acc[2][4];
    float bv1[2][4], bv2[2][4];
    int   bi1[2][4];
    #pragma unroll
    for (int mfi = 0; mfi < 2; ++mfi)
    #pragma unroll
    for (int nf = 0; nf < 4; ++nf) acc[mfi][nf] = (f32x4)0.0f;
    #pragma unroll
    for (int mfi = 0; mfi < 2; ++mfi)
    #pragma unroll
    for (int r = 0; r < 4; ++r) {
        bv1[mfi][r] = FLT_MAX; bv2[mfi][r] = FLT_MAX; bi1[mfi][r] = 0x7fffffff;
    }

    // staging map (proven): rows srow, srow+32; 16B slots s8, s8+8
    const int srow = tid >> 3;
    const int s8   = tid & 7;
    float4 stg0, stg1, stg2, stg3;

    // load step s (chunk s>>1, window s&1) into stg regs
#define LOADSTEP(s_) { \
        const f16* p = bh + (size_t)(code_base + ((s_) >> 1)*CCHUNK + srow) * BROW \
                     + ((s_) & 1)*128 + s8*8; \
        stg0 = *(const float4*)p; \
        stg1 = *(const float4*)(p + 64); \
        stg2 = *(const float4*)(p + (size_t)32*BROW); \
        stg3 = *(const float4*)(p + (size_t)32*BROW + 64); }

#define WRITEBUF(B_) { \
        *(float4*)&B_[srow*BTSTR + s8*8]          = stg0; \
        *(float4*)&B_[srow*BTSTR + (s8+8)*8]      = stg1; \
        *(float4*)&B_[(srow+32)*BTSTR + s8*8]     = stg2; \
        *(float4*)&B_[(srow+32)*BTSTR + (s8+8)*8] = stg3; }

    // prologue: step 0 -> BtA; preload step 1
    LOADSTEP(0);
    WRITEBUF(BtA);
    LOADSTEP(1);

    for (int it = 0; it < NSTEPS; it += 2) {
        // ---- first half: write step it+1 -> BtB, compute step it (BtA, sidx 0)
        __syncthreads();
        WRITEBUF(BtB);
        if (it + 2 < NSTEPS) LOADSTEP(it + 2);
        #pragma unroll
        for (int ksub = 0; ksub < 4; ++ksub) {
            const int kst = ksub;                 // sidx 0
            #pragma unroll
            for (int nf = 0; nf < 4; ++nf) {
                const f16x8 bf = *(const f16x8*)&BtA[(nf*16 + (l & 15))*BTSTR
                                                     + (ksub*4 + (l >> 4))*8];
                acc[0][nf] = __builtin_amdgcn_mfma_f32_16x16x32_f16(Ah[0][kst], bf, acc[0][nf], 0, 0, 0);
                acc[1][nf] = __builtin_amdgcn_mfma_f32_16x16x32_f16(Ah[1][kst], bf, acc[1][nf], 0, 0, 0);
            }
        }

        // ---- second half: write step it+2 -> BtA, compute step it+1 (BtB, sidx 1)
        __syncthreads();
        if (it + 2 < NSTEPS) WRITEBUF(BtA);
        if (it + 3 < NSTEPS) LOADSTEP(it + 3);
        #pragma unroll
        for (int ksub = 0; ksub < 4; ++ksub) {
            const int kst = 4 + ksub;             // sidx 1
            #pragma unroll
            for (int nf = 0; nf < 4; ++nf) {
                const f16x8 bf = *(const f16x8*)&BtB[(nf*16 + (l & 15))*BTSTR
                                                     + (ksub*4 + (l >> 4))*8];
                acc[0][nf] = __builtin_amdgcn_mfma_f32_16x16x32_f16(Ah[0][kst], bf, acc[0][nf], 0, 0, 0);
                acc[1][nf] = __builtin_amdgcn_mfma_f32_16x16x32_f16(Ah[1][kst], bf, acc[1][nf], 0, 0, 0);
            }
        }

        // fold chunk scores (codes ascend per lane -> strict '<' == np.argmin)
        {
            const int chunk = it >> 1;
            const int code0 = code_base + chunk*CCHUNK;
            #pragma unroll
            for (int nf = 0; nf < 4; ++nf) {
                const int code = code0 + nf*16 + (l & 15);
                const float c2 = cb2[code];
                #pragma unroll
                for (int mfi = 0; mfi < 2; ++mfi)
                #pragma unroll
                for (int r = 0; r < 4; ++r) {
                    float v = fmaf(acc[mfi][nf][r], -2.0f, c2);
                    if (v < bv1[mfi][r]) {
                        bv2[mfi][r] = bv1[mfi][r];
                        bv1[mfi][r] = v; bi1[mfi][r] = code;
                    } else if (v < bv2[mfi][r]) {
                        bv2[mfi][r] = v;
                    }
                    acc[mfi][nf][r] = 0.0f;
                }
            }
        }
    }
#undef LOADSTEP
#undef WRITEBUF

    // ---- reduce top-2 across the 16 code-lanes; write per-token ----
    #pragma unroll
    for (int mfi = 0; mfi < 2; ++mfi)
    #pragma unroll
    for (int r = 0; r < 4; ++r) {
        float v1 = bv1[mfi][r], v2 = bv2[mfi][r];
        int i1 = bi1[mfi][r];
        #pragma unroll
        for (int m = 1; m <= 8; m <<= 1) {
            float ov1 = __shfl_xor(v1, m, 64);
            int   oi1 = __shfl_xor(i1, m, 64);
            float ov2 = __shfl_xor(v2, m, 64);
            if (ov1 < v1 || (ov1 == v1 && oi1 < i1)) {
                v2 = fminf(v1, ov2); v1 = ov1; i1 = oi1;
            } else {
                v2 = fminf(v2, ov1);
            }
        }
        if ((l & 15) == 0) {
            int tt = n0 + wv*32 + mfi*16 + ((l >> 4) << 2) + r;
            bv1_ws[js*NTOK + tt] = v1;
            bi1_ws[js*NTOK + tt] = i1;
            bv2_ws[js*NTOK + tt] = v2;
        }
    }
}

// ---------------------------------------------------------------------------
// Kernel 3: merge splits, write idx, flag uncertain tokens (gap < MARGIN).
__global__ void combine_kernel(const float* __restrict__ bv1_ws,
                               const int* __restrict__ bi1_ws,
                               const float* __restrict__ bv2_ws,
                               int* __restrict__ idx_ws,
                               int* __restrict__ ucnt,
                               int* __restrict__ ulist,
                               unsigned long long* __restrict__ ukey)
{
    int n = blockIdx.x * 256 + threadIdx.x;
    float v1 = bv1_ws[n]; int i1 = bi1_ws[n]; float v2 = bv2_ws[n];
    #pragma unroll
    for (int js = 1; js < NSPLIT; ++js) {
        float ov1 = bv1_ws[js*NTOK + n];
        int   oi1 = bi1_ws[js*NTOK + n];
        float ov2 = bv2_ws[js*NTOK + n];
        if (ov1 < v1 || (ov1 == v1 && oi1 < i1)) {
            v2 = fminf(v1, ov2); v1 = ov1; i1 = oi1;
        } else {
            v2 = fminf(v2, ov1);
        }
    }
    idx_ws[n] = i1;
    if (v2 - v1 < MARGIN) {
        int slot = atomicAdd(ucnt, 1);
        if (slot < UCAP) {
            ulist[slot] = n;
            ukey[n] = ~0ull;
        }
    }
}

// ---------------------------------------------------------------------------
// Kernel 4: gather uncertain tokens' x vectors into dense rows.
__global__ void gathercands_kernel(const float* __restrict__ latent,
                                   const int* __restrict__ ulist,
                                   const int* __restrict__ ucnt,
                                   float* __restrict__ ucx)
{
    int cnt = *ucnt; if (cnt > UCAP) cnt = UCAP;
    int t = threadIdx.x;
    for (int i = blockIdx.x; i < cnt; i += gridDim.x) {
        int n = ulist[i];
        int b = n >> 10, hw = n & 1023;
        ucx[(size_t)i*256 + t] = latent[(size_t)b*(CHN*HH*WW) + (size_t)t*(HH*WW) + hw];
    }
}

// ---------------------------------------------------------------------------
// Kernel 5: exact fp32 refine — uncertain tokens vs ALL codes.
// (byte-identical to the passing round-12 kernel)
__global__ __launch_bounds__(256) void refine_kernel(
    const float* __restrict__ ucx, const int* __restrict__ ulist,
    const int* __restrict__ ucnt, const float* __restrict__ codebook,
    const float* __restrict__ cb2, unsigned long long* __restrict__ ukey)
{
    __shared__ float sx[RT*256];                  // 8 KB
    __shared__ unsigned long long wkey[RT][4];

    int cnt = *ucnt; if (cnt > UCAP) cnt = UCAP;
    if (cnt == 0) return;
    const int slice = blockIdx.x >> 8;            // 0..31
    const int cg    = blockIdx.x & 255;           // code group
    const int t = threadIdx.x;
    const int w = t >> 6, l = t & 63;
    const int q = t & 7;                          // dim slice
    const int code = cg * 32 + (t >> 3);

    const int chunk = (cnt + RSLICES - 1) / RSLICES;
    const int s_beg = slice * chunk;
    const int s_end = (s_beg + chunk < cnt) ? s_beg + chunk : cnt;
    const int nslice = s_end - s_beg;
    if (nslice <= 0) return;
    const int ntiles = (nslice + RT - 1) / RT;

    float4 cbr[8];
    #pragma unroll
    for (int e = 0; e < 8; ++e)
        cbr[e] = *(const float4*)&codebook[(size_t)code*DIMS + e*32 + q*4];
    const float c2 = cb2[code];

    float4 pr0, pr1;
    {
        const float4* src = (const float4*)(ucx + (size_t)s_beg*256);
        pr0 = src[t];
        pr1 = src[t + 256];
    }

    for (int tile = 0; tile < ntiles; ++tile) {
        __syncthreads();                          // sx + wkey consumers done
        *(float4*)&sx[t*4]       = pr0;           // linear: conflict-free
        *(float4*)&sx[(t+256)*4] = pr1;
        __syncthreads();

        if (tile + 1 < ntiles) {                  // T14 prefetch next tile
            const float4* src = (const float4*)(ucx + (size_t)(s_beg + (tile+1)*RT)*256);
            pr0 = src[t];
            pr1 = src[t + 256];
        }

        const int i0 = s_beg + tile * RT;
        #pragma unroll
        for (int tt = 0; tt < RT; ++tt) {
            float d0 = 0.0f, d1 = 0.0f;           // 2 chains for ILP
            #pragma unroll
            for (int e = 0; e < 8; e += 2) {
                const float4 x0 = *(const float4*)&sx[tt*256 + e*32 + q*4];
                const float4 x1 = *(const float4*)&sx[tt*256 + (e+1)*32 + q*4];
                d0 = fmaf(x0.x, cbr[e].x, d0);
                d0 = fmaf(x0.y, cbr[e].y, d0);
                d0 = fmaf(x0.z, cbr[e].z, d0);
                d0 = fmaf(x0.w, cbr[e].w, d0);
                d1 = fmaf(x1.x, cbr[e+1].x, d1);
                d1 = fmaf(x1.y, cbr[e+1].y, d1);
                d1 = fmaf(x1.z, cbr[e+1].z, d1);
                d1 = fmaf(x1.w, cbr[e+1].w, d1);
            }
            float dot = d0 + d1;
            #pragma unroll
            for (int m = 1; m <= 4; m <<= 1) dot += __shfl_xor(dot, m, 64);
            const float s = fmaf(dot, -2.0f, c2);
            unsigned mm = __float_as_uint(s);     // monotone total-order map
            mm = (mm & 0x80000000u) ? ~mm : (mm | 0x80000000u);
            unsigned long long key = ((unsigned long long)mm << 32) | (unsigned)code;
            #pragma unroll
            for (int m = 8; m <= 32; m <<= 1) {
                unsigned long long ok = __shfl_xor(key, m, 64);
                if (ok < key) key = ok;
            }
            if (l == 0) wkey[tt][w] = key;
        }
        __syncthreads();
        if (t < RT && i0 + t < s_end) {
            unsigned long long k = wkey[t][0];
            if (wkey[t][1] < k) k = wkey[t][1];
            if (wkey[t][2] < k) k = wkey[t][2];
            if (wkey[t][3] < k) k = wkey[t][3];
            atomicMin(&ukey[ulist[i0 + t]], k);
        }
    }
}

// ---------------------------------------------------------------------------
// Kernel 6: write refined indices back.
__global__ void fixup_kernel(const int* __restrict__ ulist,
                             const int* __restrict__ ucnt,
                             const unsigned long long* __restrict__ ukey,
                             int* __restrict__ idx_ws)
{
    int cnt = *ucnt; if (cnt > UCAP) cnt = UCAP;
    int i = blockIdx.x * 256 + threadIdx.x;
    if (i < cnt) {
        int n = ulist[i];
        unsigned long long k = ukey[n];
        if (k != ~0ull) idx_ws[n] = (int)(k & 0xffffffffull);
    }
}

// ---------------------------------------------------------------------------
// Kernel 7: gather codebook rows -> quantized output (NCHW), loss partials.
__global__ __launch_bounds__(256) void gather_kernel(
    const float* __restrict__ latent, const float* __restrict__ codebook,
    const int* __restrict__ idx_ws, float* __restrict__ out,
    float* __restrict__ partials)
{
    int gid = blockIdx.x * 256 + threadIdx.x;
    int o = gid * 4;
    int w0 = o & 31;
    int h  = (o >> 5) & 31;
    int c  = (o >> 10) & 255;
    int b  = o >> 18;
    int nb = (b << 10) + (h << 5) + w0;

    float4 x = *(const float4*)&latent[o];
    float4 q;
    q.x = codebook[(size_t)idx_ws[nb + 0] * DIMS + c];
    q.y = codebook[(size_t)idx_ws[nb + 1] * DIMS + c];
    q.z = codebook[(size_t)idx_ws[nb + 2] * DIMS + c];
    q.w = codebook[(size_t)idx_ws[nb + 3] * DIMS + c];
    *(float4*)&out[o] = q;

    float dx = q.x - x.x, dy = q.y - x.y, dz = q.z - x.z, dw = q.w - x.w;
    float s = dx*dx + dy*dy + dz*dz + dw*dw;
    #pragma unroll
    for (int m = 32; m >= 1; m >>= 1) s += __shfl_xor(s, m, 64);

    __shared__ float wsum[4];
    int lane = threadIdx.x & 63, wv = threadIdx.x >> 6;
    if (lane == 0) wsum[wv] = s;
    __syncthreads();
    if (threadIdx.x == 0)
        partials[blockIdx.x] = wsum[0] + wsum[1] + wsum[2] + wsum[3];
}

// ---------------------------------------------------------------------------
// Kernel 8: final loss reduction.
__global__ void loss_kernel(const float* __restrict__ partials, float* __restrict__ out) {
    __shared__ double sd[256];
    double s = 0.0;
    #pragma unroll
    for (int r = 0; r < GATHER_BLOCKS / 256; ++r)
        s += (double)partials[threadIdx.x + r * 256];
    sd[threadIdx.x] = s;
    __syncthreads();
    for (int k = 128; k >= 1; k >>= 1) {
        if (threadIdx.x < k) sd[threadIdx.x] += sd[threadIdx.x + k];
        __syncthreads();
    }
    if (threadIdx.x == 0) {
        float loss = (float)(sd[0] / (double)((size_t)NTOK * DIMS));
        out[(size_t)NTOK * DIMS + 0] = loss;
        out[(size_t)NTOK * DIMS + 1] = loss;
    }
}

// ---------------------------------------------------------------------------
extern "C" void kernel_launch(void* const* d_in, const int* in_sizes, int n_in,
                              void* d_out, int out_size, void* d_ws, size_t ws_size,
                              hipStream_t stream) {
    (void)in_sizes; (void)n_in; (void)out_size; (void)ws_size;
    const float* latent   = (const float*)d_in[0];
    const float* codebook = (const float*)d_in[1];
    float* out = (float*)d_out;
    char*  ws  = (char*)d_ws;
    char*  ob  = (char*)d_out;

    float* cb2  = (float*)(ws + WS_CB2);
    int*   idx  = (int*)(ws + WS_IDX);
    float* part = (float*)(ws + WS_PART);
    int*   ucnt = (int*)(ws + WS_UCNT);
    int*   ulist = (int*)(ws + WS_ULIST);
    unsigned long long* ukey = (unsigned long long*)(ws + WS_UKEY);  // 8-aligned

    // d_out doubles as scratch (all consumed before gather overwrites it):
    //   bh [0,4MB) f16 plane; bv1/bi1/bv2 [4,5.5MB); ucx [6,10MB)
    f16*   bh  = (f16*)ob;
    float* bv1 = (float*)(ob + DO_BV1);
    int*   bi1 = (int*)(ob + DO_BI1);
    float* bv2 = (float*)(ob + DO_BV2);
    float* ucx = (float*)(ob + DO_UCX);

    cb2pack_kernel<<<KCODES / 4, 256, 0, stream>>>(codebook, cb2, bh, ucnt);
    argmin1_kernel<<<(NTOK / MBLK) * NSPLIT, 256, 0, stream>>>(latent, bh, cb2, bv1, bi1, bv2);
    combine_kernel<<<NTOK / 256, 256, 0, stream>>>(bv1, bi1, bv2, idx, ucnt, ulist, ukey);
    gathercands_kernel<<<256, 256, 0, stream>>>(latent, ulist, ucnt, ucx);
    refine_kernel<<<RSLICES * 256, 256, 0, stream>>>(ucx, ulist, ucnt, codebook, cb2, ukey);
    fixup_kernel<<<UCAP / 256, 256, 0, stream>>>(ulist, ucnt, ukey, idx);
    gather_kernel<<<GATHER_BLOCKS, 256, 0, stream>>>(latent, codebook, idx, out, part);
    loss_kernel<<<1, 256, 0, stream>>>(part, out);
}